// Round 6
// baseline (80.160 us; speedup 1.0000x reference)
//
#include <hip/hip_runtime.h>
#include <hip/hip_bf16.h>
#include <cstdint>

#define BM 32
#define NTHREADS 640              // 10 waves
#define WS_TILE 524288            // 64 u-steps * 8192 B per weight tensor (bf16 64x64)
#define SMEM_BYTES (4*64*32*4 + 6*32*64*4)   // xS 32768 + pscr 49152 = 81920

typedef __bf16 bf16x8_t __attribute__((ext_vector_type(8)));
typedef float f32x4_t __attribute__((ext_vector_type(4)));

#define SB() __builtin_amdgcn_sched_barrier(0)

// Prep: fold scales, combine w011 + w101^T(u,v), store FRAGMENT-MAJOR per u-step:
//   ws[tile] + u*8192 + f*1024 + lane*16,  f = n*2+kf
// element (lane, j): w = 16n + (lane&15), v = 8*(lane>>4) + 32*kf + j
__global__ __launch_bounds__(256) void prep_weights(const float* __restrict__ w000,
                                                    const float* __restrict__ w110,
                                                    const float* __restrict__ w011,
                                                    const float* __restrict__ w101,
                                                    char* __restrict__ ws) {
  const float A0  = 0.011048543456039806f;   // sqrt(1/8192) ; also == ALPHA1/sqrt(3)
  const float A0I = A0 * 0.57735026918962576f;
  int t = blockIdx.x * 256 + threadIdx.x;    // 32768 threads: (u, f, lane)
  int u = t >> 9, f = (t >> 6) & 7, l = t & 63;
  int n = f >> 1, kf = f & 1;
  int w = 16 * n + (l & 15);
  int vbase = 8 * (l >> 4) + 32 * kf;
  bf16x8_t p0, p1, pc;
#pragma unroll
  for (int j = 0; j < 8; ++j) {
    int v = vbase + j;
    float a = w000[u * 4096 + v * 64 + w] * A0;
    float b = w110[u * 4096 + v * 64 + w] * A0I;
    float d = (w011[u * 4096 + v * 64 + w] + w101[v * 4096 + u * 64 + w]) * A0;
    p0[j] = (__bf16)a;
    p1[j] = (__bf16)b;
    pc[j] = (__bf16)d;
  }
  int off = u * 8192 + f * 1024 + l * 16;
  *(bf16x8_t*)(ws + off) = p0;
  *(bf16x8_t*)(ws + WS_TILE + off) = p1;
  *(bf16x8_t*)(ws + 2 * WS_TILE + off) = pc;
}

// Main: 256 blocks x 640 threads (10 waves), BM=32 rows/block, 1 block/CU.
// wave = 2*unit + kf.  unit 0: p000 ; unit 1: p110 (dot3 A) ; units 2-4: out1 k=unit-2.
// B-frags streamed GLOBAL->VGPR, triple-buffered; s-scalars prefetched from LDS;
// sched_barrier(0) pins each prefetch cluster so the compiler cannot sink the
// loads to their use (round-5 failure: VGPR=84 proved the pipeline was collapsed).
__global__ __launch_bounds__(NTHREADS, 1) void tp_main(const float* __restrict__ x,
                                                       const char* __restrict__ ws,
                                                       float* __restrict__ out) {
  extern __shared__ char smem[];
  float* xS   = (float*)smem;                 // [vec][u][b] f32, 4*64*32 = 32KB
  float* pscr = (float*)(smem + 32768);       // [6][32][64] f32 = 48KB (epilogue only)
  const int tid = threadIdx.x;
  const int wave = tid >> 6, lane = tid & 63;
  const int lr = lane & 15, lg = lane >> 4;
  const int b0 = blockIdx.x * BM;
  const int unit = wave >> 1;                 // 0..4
  const int kf = wave & 1;
  const int tsel = (unit == 0) ? 0 : ((unit == 1) ? 1 : 2);
  const char* gw = ws + tsel * WS_TILE + kf * 1024 + lane * 16;  // + u*8192 + n*2048

  // scalar table xS[vec][u][b]: vec0 = x0, vec 1+i = x1[:,:,i]
  for (int idx = tid; idx < 4 * 64 * 32; idx += NTHREADS) {
    int vec = idx >> 11, rem = idx & 2047;
    int uu = rem >> 5, bb = rem & 31;
    int col = (vec == 0) ? uu : (64 + 3 * uu + (vec - 1));
    xS[idx] = x[(b0 + bb) * 256 + col];
  }

  // per-wave x row-vectors (only this wave's kf half): v = 8*lg + 32*kf + j
  float xp[3][2][8];    // [vi][m][j]; units != 1 use vi=0 only
  if (unit == 1) {
#pragma unroll
    for (int vi = 0; vi < 3; ++vi)
#pragma unroll
      for (int m = 0; m < 2; ++m)
#pragma unroll
        for (int j = 0; j < 8; ++j) {
          int v = 8 * lg + 32 * kf + j;
          xp[vi][m][j] = x[(b0 + 16 * m + lr) * 256 + 64 + 3 * v + vi];
        }
  } else {
#pragma unroll
    for (int m = 0; m < 2; ++m)
#pragma unroll
      for (int j = 0; j < 8; ++j) {
        int v = 8 * lg + 32 * kf + j;
        int col = (unit == 0) ? v : (64 + 3 * v + (unit - 2));
        xp[0][m][j] = x[(b0 + 16 * m + lr) * 256 + col];
      }
  }

  f32x4_t acc[2][4];
#pragma unroll
  for (int m = 0; m < 2; ++m)
#pragma unroll
    for (int n = 0; n < 4; ++n) {
      f32x4_t z = {0.f, 0.f, 0.f, 0.f};
      acc[m][n] = z;
    }

  auto LOADG = [&](bf16x8_t (&bfr)[4], int uu) {
    const char* p = gw + uu * 8192;
#pragma unroll
    for (int n = 0; n < 4; ++n)
      bfr[n] = *(const bf16x8_t*)(p + n * 2048);
  };

  // prefetch s-scalars for one u-step: m0 -> sv[0..2], m1 -> sv[3..5]
  auto SLOAD = [&](float (&sv)[6], int uu) {
    if (unit == 1) {
      sv[0] = xS[1 * 2048 + uu * 32 + lr];
      sv[1] = xS[2 * 2048 + uu * 32 + lr];
      sv[2] = xS[3 * 2048 + uu * 32 + lr];
      sv[3] = xS[1 * 2048 + uu * 32 + 16 + lr];
      sv[4] = xS[2 * 2048 + uu * 32 + 16 + lr];
      sv[5] = xS[3 * 2048 + uu * 32 + 16 + lr];
    } else {
      sv[0] = xS[uu * 32 + lr];
      sv[3] = xS[uu * 32 + 16 + lr];
    }
  };

  auto STEP = [&](bf16x8_t (&bfr)[4], float (&sv)[6]) {
    bf16x8_t afr[2];
    if (unit == 1) {
#pragma unroll
      for (int j = 0; j < 8; ++j)
        afr[0][j] = (__bf16)(sv[0] * xp[0][0][j] + sv[1] * xp[1][0][j] + sv[2] * xp[2][0][j]);
#pragma unroll
      for (int j = 0; j < 8; ++j)
        afr[1][j] = (__bf16)(sv[3] * xp[0][1][j] + sv[4] * xp[1][1][j] + sv[5] * xp[2][1][j]);
    } else {
#pragma unroll
      for (int j = 0; j < 8; ++j)
        afr[0][j] = (__bf16)(sv[0] * xp[0][0][j]);
#pragma unroll
      for (int j = 0; j < 8; ++j)
        afr[1][j] = (__bf16)(sv[3] * xp[0][1][j]);
    }
#pragma unroll
    for (int m = 0; m < 2; ++m)
#pragma unroll
      for (int n = 0; n < 4; ++n)
        acc[m][n] = __builtin_amdgcn_mfma_f32_16x16x32_bf16(afr[m], bfr[n], acc[m][n], 0, 0, 0);
  };

  __syncthreads();   // xS visible; ONLY barrier before epilogue

  // triple-buffered register pipeline, hand-rotated, order PINNED by sched_barrier
  bf16x8_t B0[4], B1[4], B2[4];
  float sA[6], sB[6], sC[6];
  LOADG(B0, 0); SLOAD(sA, 0); SB();
  LOADG(B1, 1); SLOAD(sB, 1); SB();
  for (int u = 0; u < 60; u += 3) {
    LOADG(B2, u + 2); SLOAD(sC, u + 2); SB();
    STEP(B0, sA);
    LOADG(B0, u + 3); SLOAD(sA, u + 3); SB();
    STEP(B1, sB);
    LOADG(B1, u + 4); SLOAD(sB, u + 4); SB();
    STEP(B2, sC);
  }
  LOADG(B2, 62); SLOAD(sC, 62); SB();
  STEP(B0, sA);
  LOADG(B0, 63); SLOAD(sA, 63); SB();
  STEP(B1, sB);
  STEP(B2, sC);
  STEP(B0, sA);

  // ---- epilogue (pscr disjoint from xS: no alias with free-running waves) ----
  // phase 1: kf=1 waves dump acc
  if (kf == 1) {
#pragma unroll
    for (int m = 0; m < 2; ++m)
#pragma unroll
      for (int n = 0; n < 4; ++n)
#pragma unroll
        for (int r = 0; r < 4; ++r)
          pscr[unit * 2048 + (16 * m + 4 * lg + r) * 64 + 16 * n + lr] = acc[m][n][r];
  }
  __syncthreads();
  // phase 2: kf=0 waves fold in their pair's half; unit 1 republishes p110 sum
  if (kf == 0) {
#pragma unroll
    for (int m = 0; m < 2; ++m)
#pragma unroll
      for (int n = 0; n < 4; ++n)
#pragma unroll
        for (int r = 0; r < 4; ++r)
          acc[m][n][r] += pscr[unit * 2048 + (16 * m + 4 * lg + r) * 64 + 16 * n + lr];
    if (unit == 1) {
#pragma unroll
      for (int m = 0; m < 2; ++m)
#pragma unroll
        for (int n = 0; n < 4; ++n)
#pragma unroll
          for (int r = 0; r < 4; ++r)
            pscr[5 * 2048 + (16 * m + 4 * lg + r) * 64 + 16 * n + lr] = acc[m][n][r];
    }
  }
  __syncthreads();
  // phase 3: stores
  if (wave == 0) {                  // out0 = p000 + p110
#pragma unroll
    for (int m = 0; m < 2; ++m)
#pragma unroll
      for (int n = 0; n < 4; ++n)
#pragma unroll
        for (int r = 0; r < 4; ++r) {
          int row = 16 * m + 4 * lg + r, col = 16 * n + lr;
          out[(b0 + row) * 256 + col] = acc[m][n][r] + pscr[5 * 2048 + row * 64 + col];
        }
  } else if (kf == 0 && unit >= 2) {  // out1, k = unit-2
    const int k = unit - 2;
#pragma unroll
    for (int m = 0; m < 2; ++m)
#pragma unroll
      for (int n = 0; n < 4; ++n)
#pragma unroll
        for (int r = 0; r < 4; ++r) {
          int row = 16 * m + 4 * lg + r, col = 16 * n + lr;
          out[(b0 + row) * 256 + 64 + 3 * col + k] = acc[m][n][r];
        }
  }
}

extern "C" void kernel_launch(void* const* d_in, const int* in_sizes, int n_in,
                              void* d_out, int out_size, void* d_ws, size_t ws_size,
                              hipStream_t stream) {
  const float* x    = (const float*)d_in[0];
  const float* w000 = (const float*)d_in[1];
  const float* w110 = (const float*)d_in[2];
  const float* w011 = (const float*)d_in[3];
  const float* w101 = (const float*)d_in[4];
  float* out = (float*)d_out;
  char* ws = (char*)d_ws;

  prep_weights<<<128, 256, 0, stream>>>(w000, w110, w011, w101, ws);

  hipFuncSetAttribute((const void*)tp_main, hipFuncAttributeMaxDynamicSharedMemorySize, SMEM_BYTES);
  tp_main<<<256, NTHREADS, SMEM_BYTES, stream>>>(x, ws, out);
}

// Round 7
// 68.073 us; speedup vs baseline: 1.1776x; 1.1776x over previous
//
#include <hip/hip_runtime.h>
#include <hip/hip_bf16.h>
#include <cstdint>

#define BM 16
#define NTHREADS 640              // 10 waves
#define NBLOCKS 512               // 2 blocks/CU
#define WS_TILE 524288            // 64 u-steps * 8192 B per weight tensor (bf16 64x64)

typedef __bf16 bf16x8_t __attribute__((ext_vector_type(8)));
typedef float f32x4_t __attribute__((ext_vector_type(4)));

// Prep: fold scales, combine w011 + w101^T(u,v), store FRAGMENT-MAJOR per u-step:
//   ws[tile] + u*8192 + f*1024 + lane*16,  f = n*2+kf
// element (lane, j): w = 16n + (lane&15), v = 8*(lane>>4) + 32*kf + j
__global__ __launch_bounds__(256) void prep_weights(const float* __restrict__ w000,
                                                    const float* __restrict__ w110,
                                                    const float* __restrict__ w011,
                                                    const float* __restrict__ w101,
                                                    char* __restrict__ ws) {
  const float A0  = 0.011048543456039806f;   // sqrt(1/8192) ; also == ALPHA1/sqrt(3)
  const float A0I = A0 * 0.57735026918962576f;
  int t = blockIdx.x * 256 + threadIdx.x;    // 32768 threads: (u, f, lane)
  int u = t >> 9, f = (t >> 6) & 7, l = t & 63;
  int n = f >> 1, kf = f & 1;
  int w = 16 * n + (l & 15);
  int vbase = 8 * (l >> 4) + 32 * kf;
  bf16x8_t p0, p1, pc;
#pragma unroll
  for (int j = 0; j < 8; ++j) {
    int v = vbase + j;
    float a = w000[u * 4096 + v * 64 + w] * A0;
    float b = w110[u * 4096 + v * 64 + w] * A0I;
    float d = (w011[u * 4096 + v * 64 + w] + w101[v * 4096 + u * 64 + w]) * A0;
    p0[j] = (__bf16)a;
    p1[j] = (__bf16)b;
    pc[j] = (__bf16)d;
  }
  int off = u * 8192 + f * 1024 + l * 16;
  *(bf16x8_t*)(ws + off) = p0;
  *(bf16x8_t*)(ws + WS_TILE + off) = p1;
  *(bf16x8_t*)(ws + 2 * WS_TILE + off) = pc;
}

// Main: 512 blocks x 640 threads (10 waves), BM=16 rows/block, 2 blocks/CU.
// wave = 2*unit + kf.  unit 0: p000 ; unit 1: p110 (dot3 A) ; units 2-4: out1 k=unit-2.
// Each wave: ONE K-half (kf), 4 B-frags/step global->VGPR (L1/L2-resident),
// compiler-scheduled (r5-proven no-spill). TLP (5 waves/SIMD) hides latency.
__global__ __launch_bounds__(NTHREADS, 5) void tp_main(const float* __restrict__ x,
                                                       const char* __restrict__ ws,
                                                       float* __restrict__ out) {
  __shared__ float xS[4 * 64 * BM];        // [vec][u][b] f32 = 16KB
  __shared__ float pscr[6 * BM * 64];      // [6][16][64] f32 = 24KB (epilogue)
  const int tid = threadIdx.x;
  const int wave = tid >> 6, lane = tid & 63;
  const int lr = lane & 15, lg = lane >> 4;
  const int b0 = blockIdx.x * BM;
  const int unit = wave >> 1;              // 0..4
  const int kf = wave & 1;
  const int tsel = (unit == 0) ? 0 : ((unit == 1) ? 1 : 2);
  const char* gw = ws + tsel * WS_TILE + kf * 1024 + lane * 16;  // + u*8192 + n*2048

  // scalar table xS[vec][u][b]: vec0 = x0, vec 1+i = x1[:,:,i]
  for (int idx = tid; idx < 4 * 64 * BM; idx += NTHREADS) {
    int vec = idx >> 10, rem = idx & 1023;
    int uu = rem >> 4, bb = rem & 15;
    int col = (vec == 0) ? uu : (64 + 3 * uu + (vec - 1));
    xS[idx] = x[(b0 + bb) * 256 + col];
  }

  // per-wave x row-vectors (this wave's kf half): v = 8*lg + 32*kf + j, row = b0+lr
  float xp[3][8];    // units != 1 use [0] only
  if (unit == 1) {
#pragma unroll
    for (int vi = 0; vi < 3; ++vi)
#pragma unroll
      for (int j = 0; j < 8; ++j) {
        int v = 8 * lg + 32 * kf + j;
        xp[vi][j] = x[(b0 + lr) * 256 + 64 + 3 * v + vi];
      }
  } else {
#pragma unroll
    for (int j = 0; j < 8; ++j) {
      int v = 8 * lg + 32 * kf + j;
      int col = (unit == 0) ? v : (64 + 3 * v + (unit - 2));
      xp[0][j] = x[(b0 + lr) * 256 + col];
    }
  }

  f32x4_t acc[4];
#pragma unroll
  for (int n = 0; n < 4; ++n) {
    f32x4_t z = {0.f, 0.f, 0.f, 0.f};
    acc[n] = z;
  }

  auto LOADG = [&](bf16x8_t (&bfr)[4], int uu) {
    const char* p = gw + uu * 8192;
#pragma unroll
    for (int n = 0; n < 4; ++n)
      bfr[n] = *(const bf16x8_t*)(p + n * 2048);
  };

  auto SLOAD = [&](float (&sv)[3], int uu) {
    if (unit == 1) {
      sv[0] = xS[1 * 1024 + uu * 16 + lr];
      sv[1] = xS[2 * 1024 + uu * 16 + lr];
      sv[2] = xS[3 * 1024 + uu * 16 + lr];
    } else {
      sv[0] = xS[uu * 16 + lr];
    }
  };

  auto STEP = [&](bf16x8_t (&bfr)[4], float (&sv)[3]) {
    bf16x8_t afr;
    if (unit == 1) {
#pragma unroll
      for (int j = 0; j < 8; ++j)
        afr[j] = (__bf16)(sv[0] * xp[0][j] + sv[1] * xp[1][j] + sv[2] * xp[2][j]);
    } else {
#pragma unroll
      for (int j = 0; j < 8; ++j)
        afr[j] = (__bf16)(sv[0] * xp[0][j]);
    }
#pragma unroll
    for (int n = 0; n < 4; ++n)
      acc[n] = __builtin_amdgcn_mfma_f32_16x16x32_bf16(afr, bfr[n], acc[n], 0, 0, 0);
  };

  __syncthreads();   // xS visible; only barrier before epilogue

  // double-buffered rotation (compiler-scheduled)
  bf16x8_t B0[4], B1[4];
  float sA[3], sB[3];
  LOADG(B0, 0); SLOAD(sA, 0);
  for (int u = 0; u < 62; u += 2) {
    LOADG(B1, u + 1); SLOAD(sB, u + 1);
    STEP(B0, sA);
    LOADG(B0, u + 2); SLOAD(sA, u + 2);
    STEP(B1, sB);
  }
  LOADG(B1, 63); SLOAD(sB, 63);
  STEP(B0, sA);
  STEP(B1, sB);

  // ---- epilogue ----
  // phase 1: kf=1 waves dump acc
  if (kf == 1) {
#pragma unroll
    for (int n = 0; n < 4; ++n)
#pragma unroll
      for (int r = 0; r < 4; ++r)
        pscr[unit * 1024 + (4 * lg + r) * 64 + 16 * n + lr] = acc[n][r];
  }
  __syncthreads();
  // phase 2: kf=0 waves fold in their pair's half; unit 1 republishes p110 sum
  if (kf == 0) {
#pragma unroll
    for (int n = 0; n < 4; ++n)
#pragma unroll
      for (int r = 0; r < 4; ++r)
        acc[n][r] += pscr[unit * 1024 + (4 * lg + r) * 64 + 16 * n + lr];
    if (unit == 1) {
#pragma unroll
      for (int n = 0; n < 4; ++n)
#pragma unroll
        for (int r = 0; r < 4; ++r)
          pscr[5 * 1024 + (4 * lg + r) * 64 + 16 * n + lr] = acc[n][r];
    }
  }
  __syncthreads();
  // phase 3: stores
  if (wave == 0) {                  // out0 = p000 + p110
#pragma unroll
    for (int n = 0; n < 4; ++n)
#pragma unroll
      for (int r = 0; r < 4; ++r) {
        int row = 4 * lg + r, col = 16 * n + lr;
        out[(b0 + row) * 256 + col] = acc[n][r] + pscr[5 * 1024 + row * 64 + col];
      }
  } else if (kf == 0 && unit >= 2) {  // out1, k = unit-2
    const int k = unit - 2;
#pragma unroll
    for (int n = 0; n < 4; ++n)
#pragma unroll
      for (int r = 0; r < 4; ++r) {
        int row = 4 * lg + r, col = 16 * n + lr;
        out[(b0 + row) * 256 + 64 + 3 * col + k] = acc[n][r];
      }
  }
}

extern "C" void kernel_launch(void* const* d_in, const int* in_sizes, int n_in,
                              void* d_out, int out_size, void* d_ws, size_t ws_size,
                              hipStream_t stream) {
  const float* x    = (const float*)d_in[0];
  const float* w000 = (const float*)d_in[1];
  const float* w110 = (const float*)d_in[2];
  const float* w011 = (const float*)d_in[3];
  const float* w101 = (const float*)d_in[4];
  float* out = (float*)d_out;
  char* ws = (char*)d_ws;

  prep_weights<<<128, 256, 0, stream>>>(w000, w110, w011, w101, ws);
  tp_main<<<NBLOCKS, NTHREADS, 0, stream>>>(x, ws, out);
}

// Round 8
// 52.265 us; speedup vs baseline: 1.5337x; 1.3025x over previous
//
#include <hip/hip_runtime.h>
#include <hip/hip_bf16.h>
#include <cstdint>

#define BM 32
#define NTHREADS 640              // 10 waves
#define WS_TILE 524288            // 64 u-steps * 8192 B per weight tensor (bf16 64x64)
#define WAVE_BUF 4096             // one kf-half tile per wave per u-step
#define NBUF 3
#define STAGE_BYTES (10 * NBUF * WAVE_BUF)          // 122880
#define SMEM_BYTES (STAGE_BYTES + 4 * 64 * 32 * 4)  // +32768 = 155648

typedef __bf16 bf16x8_t __attribute__((ext_vector_type(8)));
typedef float f32x4_t __attribute__((ext_vector_type(4)));

__device__ __forceinline__ void async_ld16(const void* g, void* l) {
  __builtin_amdgcn_global_load_lds((const __attribute__((address_space(1))) unsigned int*)g,
                                   (__attribute__((address_space(3))) unsigned int*)l,
                                   16, 0, 0);
}

// per-wave counted waits: no barriers anywhere in the u-loop
#define WAIT4() asm volatile("s_waitcnt vmcnt(4)" ::: "memory")
#define WAIT0() asm volatile("s_waitcnt vmcnt(0)" ::: "memory")

// Prep: fold scales, combine w011 + w101^T(u,v), store FRAGMENT-MAJOR per u-step:
//   ws[tile] + u*8192 + f*1024 + lane*16,  f = n*2+kf
// element (lane, j): w = 16n + (lane&15), v = 8*(lane>>4) + 32*kf + j
__global__ __launch_bounds__(256) void prep_weights(const float* __restrict__ w000,
                                                    const float* __restrict__ w110,
                                                    const float* __restrict__ w011,
                                                    const float* __restrict__ w101,
                                                    char* __restrict__ ws) {
  const float A0  = 0.011048543456039806f;   // sqrt(1/8192) ; also == ALPHA1/sqrt(3)
  const float A0I = A0 * 0.57735026918962576f;
  int t = blockIdx.x * 256 + threadIdx.x;    // 32768 threads: (u, f, lane)
  int u = t >> 9, f = (t >> 6) & 7, l = t & 63;
  int n = f >> 1, kf = f & 1;
  int w = 16 * n + (l & 15);
  int vbase = 8 * (l >> 4) + 32 * kf;
  bf16x8_t p0, p1, pc;
#pragma unroll
  for (int j = 0; j < 8; ++j) {
    int v = vbase + j;
    float a = w000[u * 4096 + v * 64 + w] * A0;
    float b = w110[u * 4096 + v * 64 + w] * A0I;
    float d = (w011[u * 4096 + v * 64 + w] + w101[v * 4096 + u * 64 + w]) * A0;
    p0[j] = (__bf16)a;
    p1[j] = (__bf16)b;
    pc[j] = (__bf16)d;
  }
  int off = u * 8192 + f * 1024 + l * 16;
  *(bf16x8_t*)(ws + off) = p0;
  *(bf16x8_t*)(ws + WS_TILE + off) = p1;
  *(bf16x8_t*)(ws + 2 * WS_TILE + off) = pc;
}

// Main: 256 blocks x 640 threads (10 waves), BM=32, 1 block/CU.
// wave = 2*unit + kf.  unit 0: p000 ; unit 1: p110 (dot3 A) ; units 2-4: out1 k=unit-2.
// Each wave stages ITS OWN kf-half weight tile (4KB) via global_load_lds into a
// wave-private triple buffer; counted vmcnt(4) per phase; ZERO barriers in loop.
__global__ __launch_bounds__(NTHREADS) void tp_main(const float* __restrict__ x,
                                                    const char* __restrict__ ws,
                                                    float* __restrict__ out) {
  extern __shared__ char smem[];
  float* xS   = (float*)(smem + STAGE_BYTES);  // [vec][u][b] f32, 4*64*32 = 32KB
  float* pscr = (float*)smem;                  // epilogue scratch, overlaps staging
  const int tid = threadIdx.x;
  const int wave = tid >> 6, lane = tid & 63;
  const int lr = lane & 15, lg = lane >> 4;
  const int b0 = blockIdx.x * BM;
  const int unit = wave >> 1;                  // 0..4
  const int kf = wave & 1;
  const int tsel = (unit == 0) ? 0 : ((unit == 1) ? 1 : 2);
  const char* gw = ws + tsel * WS_TILE + kf * 1024 + lane * 16;  // + u*8192 + n*2048
  char* myb = smem + wave * (NBUF * WAVE_BUF);

  // stage this wave's kf-half of tile uu into private buffer bsel
  auto STAGE = [&](int uu, int bsel) {
    const char* g = gw + uu * 8192;
    char* l = myb + bsel * WAVE_BUF + lane * 16;
#pragma unroll
    for (int n = 0; n < 4; ++n)
      async_ld16(g + n * 2048, l + n * 1024);
  };

  auto LOADB = [&](bf16x8_t (&bfr)[4], int bsel) {
    const char* p = myb + bsel * WAVE_BUF + lane * 16;
#pragma unroll
    for (int n = 0; n < 4; ++n)
      bfr[n] = *(const bf16x8_t*)(p + n * 1024);
  };

  // scalar table xS[vec][u][b]: vec0 = x0, vec 1+i = x1[:,:,i]
  for (int idx = tid; idx < 4 * 64 * 32; idx += NTHREADS) {
    int vec = idx >> 11, rem = idx & 2047;
    int uu = rem >> 5, bb = rem & 31;
    int col = (vec == 0) ? uu : (64 + 3 * uu + (vec - 1));
    xS[idx] = x[(b0 + bb) * 256 + col];
  }

  // per-wave x row-vectors (this wave's kf half): v = 8*lg + 32*kf + j
  float xp[3][2][8];    // [vi][m][j]; units != 1 use vi=0 only
  if (unit == 1) {
#pragma unroll
    for (int vi = 0; vi < 3; ++vi)
#pragma unroll
      for (int m = 0; m < 2; ++m)
#pragma unroll
        for (int j = 0; j < 8; ++j) {
          int v = 8 * lg + 32 * kf + j;
          xp[vi][m][j] = x[(b0 + 16 * m + lr) * 256 + 64 + 3 * v + vi];
        }
  } else {
#pragma unroll
    for (int m = 0; m < 2; ++m)
#pragma unroll
      for (int j = 0; j < 8; ++j) {
        int v = 8 * lg + 32 * kf + j;
        int col = (unit == 0) ? v : (64 + 3 * v + (unit - 2));
        xp[0][m][j] = x[(b0 + 16 * m + lr) * 256 + col];
      }
  }

  f32x4_t acc[2][4];
#pragma unroll
  for (int m = 0; m < 2; ++m)
#pragma unroll
    for (int n = 0; n < 4; ++n) {
      f32x4_t z = {0.f, 0.f, 0.f, 0.f};
      acc[m][n] = z;
    }

  auto STEP = [&](bf16x8_t (&bfr)[4], int uu) {
    bf16x8_t afr[2];
    if (unit == 1) {
#pragma unroll
      for (int m = 0; m < 2; ++m) {
        float s0 = xS[1 * 2048 + uu * 32 + 16 * m + lr];
        float s1 = xS[2 * 2048 + uu * 32 + 16 * m + lr];
        float s2 = xS[3 * 2048 + uu * 32 + 16 * m + lr];
#pragma unroll
        for (int j = 0; j < 8; ++j)
          afr[m][j] = (__bf16)(s0 * xp[0][m][j] + s1 * xp[1][m][j] + s2 * xp[2][m][j]);
      }
    } else {
#pragma unroll
      for (int m = 0; m < 2; ++m) {
        float s = xS[uu * 32 + 16 * m + lr];
#pragma unroll
        for (int j = 0; j < 8; ++j)
          afr[m][j] = (__bf16)(s * xp[0][m][j]);
      }
    }
#pragma unroll
    for (int m = 0; m < 2; ++m)
#pragma unroll
      for (int n = 0; n < 4; ++n)
        acc[m][n] = __builtin_amdgcn_mfma_f32_16x16x32_bf16(afr[m], bfr[n], acc[m][n], 0, 0, 0);
  };

  __syncthreads();   // xS visible; LAST barrier before epilogue

  // prologue: tiles 0,1 in flight (wave-private)
  STAGE(0, 0);
  STAGE(1, 1);

  bf16x8_t bfr[4];
  // phase u: WAIT4 (tile u landed; u+1,u+2 in flight) -> read -> stage u+2 -> compute
  for (int u = 0; u < 60; u += 3) {
    WAIT4(); LOADB(bfr, 0); STAGE(u + 2, 2); STEP(bfr, u);
    WAIT4(); LOADB(bfr, 1); STAGE(u + 3, 0); STEP(bfr, u + 1);
    WAIT4(); LOADB(bfr, 2); STAGE(u + 4, 1); STEP(bfr, u + 2);
  }
  WAIT4(); LOADB(bfr, 0); STAGE(62, 2); STEP(bfr, 60);
  WAIT4(); LOADB(bfr, 1); STAGE(63, 0); STEP(bfr, 61);
  WAIT4(); LOADB(bfr, 2); STEP(bfr, 62);
  WAIT0(); LOADB(bfr, 0); STEP(bfr, 63);

  // ---- epilogue (pscr overlaps staging LDS: barrier first, all waves done) ----
  __syncthreads();
  // phase 1: kf=1 waves dump acc
  if (kf == 1) {
#pragma unroll
    for (int m = 0; m < 2; ++m)
#pragma unroll
      for (int n = 0; n < 4; ++n)
#pragma unroll
        for (int r = 0; r < 4; ++r)
          pscr[unit * 2048 + (16 * m + 4 * lg + r) * 64 + 16 * n + lr] = acc[m][n][r];
  }
  __syncthreads();
  // phase 2: kf=0 waves fold in their pair's half; unit 1 republishes p110 sum
  if (kf == 0) {
#pragma unroll
    for (int m = 0; m < 2; ++m)
#pragma unroll
      for (int n = 0; n < 4; ++n)
#pragma unroll
        for (int r = 0; r < 4; ++r)
          acc[m][n][r] += pscr[unit * 2048 + (16 * m + 4 * lg + r) * 64 + 16 * n + lr];
    if (unit == 1) {
#pragma unroll
      for (int m = 0; m < 2; ++m)
#pragma unroll
        for (int n = 0; n < 4; ++n)
#pragma unroll
          for (int r = 0; r < 4; ++r)
            pscr[5 * 2048 + (16 * m + 4 * lg + r) * 64 + 16 * n + lr] = acc[m][n][r];
    }
  }
  __syncthreads();
  // phase 3: stores
  if (wave == 0) {                  // out0 = p000 + p110
#pragma unroll
    for (int m = 0; m < 2; ++m)
#pragma unroll
      for (int n = 0; n < 4; ++n)
#pragma unroll
        for (int r = 0; r < 4; ++r) {
          int row = 16 * m + 4 * lg + r, col = 16 * n + lr;
          out[(b0 + row) * 256 + col] = acc[m][n][r] + pscr[5 * 2048 + row * 64 + col];
        }
  } else if (kf == 0 && unit >= 2) {  // out1, k = unit-2
    const int k = unit - 2;
#pragma unroll
    for (int m = 0; m < 2; ++m)
#pragma unroll
      for (int n = 0; n < 4; ++n)
#pragma unroll
        for (int r = 0; r < 4; ++r) {
          int row = 16 * m + 4 * lg + r, col = 16 * n + lr;
          out[(b0 + row) * 256 + 64 + 3 * col + k] = acc[m][n][r];
        }
  }
}

extern "C" void kernel_launch(void* const* d_in, const int* in_sizes, int n_in,
                              void* d_out, int out_size, void* d_ws, size_t ws_size,
                              hipStream_t stream) {
  const float* x    = (const float*)d_in[0];
  const float* w000 = (const float*)d_in[1];
  const float* w110 = (const float*)d_in[2];
  const float* w011 = (const float*)d_in[3];
  const float* w101 = (const float*)d_in[4];
  float* out = (float*)d_out;
  char* ws = (char*)d_ws;

  prep_weights<<<128, 256, 0, stream>>>(w000, w110, w011, w101, ws);

  hipFuncSetAttribute((const void*)tp_main, hipFuncAttributeMaxDynamicSharedMemorySize, SMEM_BYTES);
  tp_main<<<256, NTHREADS, SMEM_BYTES, stream>>>(x, ws, out);
}